// Round 1
// baseline (43.452 us; speedup 1.0000x reference)
//
#include <hip/hip_runtime.h>
#include <hip/hip_bf16.h>

#define Bn 16
#define Sn 2048
#define Hn 768
#define Dn 128
#define AT 8
#define IT 32
#define NSEG (Bn*AT*IT)      // 4096
#define NCHUNK 8
#define CHTOK (Sn/NCHUNK)    // 256

typedef __attribute__((ext_vector_type(4))) float f32x4;
typedef __attribute__((ext_vector_type(4))) int   i32x4;
typedef __attribute__((ext_vector_type(8))) short bf16x8;
typedef __attribute__((ext_vector_type(4))) short s16x4;

__device__ __forceinline__ unsigned short f2bf(float f){
  union { float f; unsigned u; } v; v.f = f;
  unsigned r = v.u + 0x7FFFu + ((v.u >> 16) & 1u);   // round-to-nearest-even
  return (unsigned short)(r >> 16);
}

// ---- kernel 0: W [H][D] fp32 -> Wt [D][H] bf16 (transposed, for contiguous B-fragments) ----
__global__ __launch_bounds__(256) void k_prep(const float* __restrict__ W,
                                              unsigned short* __restrict__ Wt){
  int gid = blockIdx.x*256 + threadIdx.x;
  if (gid >= Hn*Dn) return;
  int d = gid / Hn;
  int k = gid - d*Hn;
  Wt[gid] = f2bf(W[k*Dn + d]);
}

// ---- kernel 1: h = X @ W + b  (bf16 MFMA 16x16x32, fp32 out) ----
// BM=64, BN=128(all of D), BK=64. 256 threads = 4 waves; wave w -> cols [w*32, w*32+32).
// LDS tiles XOR-swizzled (byte ^= (row&7)<<4) so ds_read_b128 fragments are conflict-free.
__global__ __launch_bounds__(256) void k_gemm(const float* __restrict__ X,
        const unsigned short* __restrict__ Wt, const float* __restrict__ bias,
        float* __restrict__ Hout){
  __shared__ unsigned char sA[2][64*128];    // [row][128B of swizzled bf16 k]
  __shared__ unsigned char sB[2][128*128];   // [col][128B of swizzled bf16 k]
  const int tid  = threadIdx.x;
  const int lane = tid & 63;
  const int wave = tid >> 6;
  const int m0 = blockIdx.x * 64;

  // staging maps
  const int ar = tid >> 2, akq = tid & 3;    // A: row, k-quarter
  const int bc = tid >> 1, bkh = tid & 1;    // B: col, k-half
  const float*          Ap = X  + (size_t)(m0 + ar)*Hn + akq*4;
  const unsigned short* Bp = Wt + (size_t)bc*Hn + bkh*32;

  int aw[4], bw[4];
  #pragma unroll
  for (int c=0;c<4;c++) aw[c] = ar*128 + ((akq*8 + c*32) ^ ((ar&7)<<4));   // 8B chunks
  #pragma unroll
  for (int c=0;c<4;c++) bw[c] = bc*128 + ((bkh*64 + c*16) ^ ((bc&7)<<4));  // 16B chunks

  // fragment read bases
  int abase[4], aswz[4];
  #pragma unroll
  for (int mi=0;mi<4;mi++){
    int row = mi*16 + (lane&15);
    abase[mi] = row*128; aswz[mi] = (row&7)<<4;
  }
  int bbase[2], bswz[2];
  #pragma unroll
  for (int ni=0;ni<2;ni++){
    int col = wave*32 + ni*16 + (lane&15);
    bbase[ni] = col*128; bswz[ni] = (col&7)<<4;
  }
  const int kblk = (lane>>4)*16;

  f32x4 acc[4][2];
  #pragma unroll
  for (int mi=0;mi<4;mi++)
    #pragma unroll
    for (int ni=0;ni<2;ni++) acc[mi][ni] = (f32x4){0.f,0.f,0.f,0.f};

  f32x4 av[4]; i32x4 bv[4];
  // prologue: stage K-step 0 into buffer 0
  #pragma unroll
  for (int c=0;c<4;c++) av[c] = *(const f32x4*)(Ap + c*16);
  #pragma unroll
  for (int c=0;c<4;c++) bv[c] = *(const i32x4*)(Bp + c*8);
  #pragma unroll
  for (int c=0;c<4;c++){
    s16x4 t;
    t[0]=(short)f2bf(av[c][0]); t[1]=(short)f2bf(av[c][1]);
    t[2]=(short)f2bf(av[c][2]); t[3]=(short)f2bf(av[c][3]);
    *(s16x4*)&sA[0][aw[c]] = t;
  }
  #pragma unroll
  for (int c=0;c<4;c++) *(i32x4*)&sB[0][bw[c]] = bv[c];
  __syncthreads();

  int cur = 0;
  for (int step=0; step<12; ++step){
    if (step < 11){  // prefetch next K-step to regs (latency hides under MFMA)
      #pragma unroll
      for (int c=0;c<4;c++) av[c] = *(const f32x4*)(Ap + (step+1)*64 + c*16);
      #pragma unroll
      for (int c=0;c<4;c++) bv[c] = *(const i32x4*)(Bp + (step+1)*64 + c*8);
    }
    #pragma unroll
    for (int ks=0; ks<2; ++ks){
      bf16x8 af[4], bfv[2];
      #pragma unroll
      for (int mi=0;mi<4;mi++)
        af[mi] = *(const bf16x8*)&sA[cur][abase[mi] + ((ks*64 + kblk) ^ aswz[mi])];
      #pragma unroll
      for (int ni=0;ni<2;ni++)
        bfv[ni] = *(const bf16x8*)&sB[cur][bbase[ni] + ((ks*64 + kblk) ^ bswz[ni])];
      #pragma unroll
      for (int mi=0;mi<4;mi++)
        #pragma unroll
        for (int ni=0;ni<2;ni++)
          acc[mi][ni] = __builtin_amdgcn_mfma_f32_16x16x32_bf16(af[mi], bfv[ni], acc[mi][ni], 0, 0, 0);
    }
    if (step < 11){  // write next tile to other buffer (WAR-safe: prev barrier separates)
      #pragma unroll
      for (int c=0;c<4;c++){
        s16x4 t;
        t[0]=(short)f2bf(av[c][0]); t[1]=(short)f2bf(av[c][1]);
        t[2]=(short)f2bf(av[c][2]); t[3]=(short)f2bf(av[c][3]);
        *(s16x4*)&sA[cur^1][aw[c]] = t;
      }
      #pragma unroll
      for (int c=0;c<4;c++) *(i32x4*)&sB[cur^1][bw[c]] = bv[c];
    }
    __syncthreads();
    cur ^= 1;
  }

  // epilogue: C/D layout col=lane&15, row=(lane>>4)*4+r  (m89-verified)
  #pragma unroll
  for (int ni=0;ni<2;ni++){
    int col = wave*32 + ni*16 + (lane&15);
    float bb = bias[col];
    #pragma unroll
    for (int mi=0;mi<4;mi++){
      int row0 = m0 + mi*16 + (lane>>4)*4;
      #pragma unroll
      for (int r=0;r<4;r++)
        Hout[(size_t)(row0 + r)*Dn + col] = acc[mi][ni][r] + bb;
    }
  }
}

// ---- kernel 2: per-(batch,attr,chunk) partial segment sums over h ----
// Deterministic: ordered ballot-compacted token list, sequential accumulation per thread.
__global__ __launch_bounds__(128) void k_scan(const int* __restrict__ attr,
        const int* __restrict__ item, const float* __restrict__ Hsrc,
        float* __restrict__ psums, float* __restrict__ pcnts){
  __shared__ float ssum[IT][Dn];   // 16 KB
  __shared__ int   scnt[IT];
  __shared__ int   slist[CHTOK];

  const int wg  = blockIdx.x;        // ((b*8 + a)*NCHUNK + c)
  const int c   = wg & (NCHUNK-1);
  const int a   = (wg / NCHUNK) & 7;
  const int b   = wg / (NCHUNK*AT);
  const int tid = threadIdx.x;       // 0..127 -> dim d
  const int lane = tid & 63;

  for (int i = tid; i < IT*Dn; i += 128) (&ssum[0][0])[i] = 0.f;
  if (tid < IT) scnt[tid] = 0;

  // build ordered match list (both waves compute identical lists; same-value writes benign)
  const int tglob0 = b*Sn + c*CHTOK;
  int base = 0;
  #pragma unroll
  for (int g=0; g<CHTOK/64; ++g){
    int t = tglob0 + g*64 + lane;
    int avv = attr[t], ivv = item[t];
    bool m = (avv == a+1) && (ivv >= 1) && (ivv <= IT);
    unsigned long long mask = __ballot(m);
    int pos = base + __popcll(mask & ((1ull<<lane)-1ull));
    if (m) slist[pos] = ((ivv-1) << 16) | (c*CHTOK + g*64 + lane);
    base += __popcll(mask);
  }
  const int nm = base;
  __syncthreads();

  // counts: integer LDS atomics (order-independent -> deterministic)
  for (int e = tid; e < nm; e += 128) atomicAdd(&scnt[slist[e] >> 16], 1);

  // accumulate: 4-deep load pipelining, fixed order per thread
  const float* hb = Hsrc + (size_t)b*Sn*Dn;
  int e = 0;
  for (; e + 4 <= nm; e += 4){
    int p0=slist[e], p1=slist[e+1], p2=slist[e+2], p3=slist[e+3];
    float v0 = hb[(p0 & 0xffff)*Dn + tid];
    float v1 = hb[(p1 & 0xffff)*Dn + tid];
    float v2 = hb[(p2 & 0xffff)*Dn + tid];
    float v3 = hb[(p3 & 0xffff)*Dn + tid];
    ssum[p0>>16][tid] += v0;
    ssum[p1>>16][tid] += v1;
    ssum[p2>>16][tid] += v2;
    ssum[p3>>16][tid] += v3;
  }
  for (; e < nm; ++e){
    int p = slist[e];
    ssum[p>>16][tid] += hb[(p & 0xffff)*Dn + tid];
  }
  __syncthreads();

  float* outp = psums + (size_t)wg*IT*Dn;
  for (int i=0;i<IT;i++) outp[i*Dn + tid] = ssum[i][tid];
  if (tid < IT) pcnts[wg*IT + tid] = (float)scnt[tid];
}

// ---- kernel 3: combine partials (fixed order), divide, write pooled + empty ----
__global__ __launch_bounds__(256) void k_comb(const float* __restrict__ psums,
        const float* __restrict__ pcnts, float* __restrict__ pooled,
        float* __restrict__ empty){
  int gid = blockIdx.x*256 + threadIdx.x;   // 0 .. NSEG*Dn-1
  int seg = gid >> 7;       // b*256 + a*32 + i
  int d   = gid & 127;
  int ba  = seg >> 5;       // b*8 + a
  int i   = seg & 31;
  float s = 0.f, cnt = 0.f;
  #pragma unroll
  for (int cch=0; cch<NCHUNK; ++cch){
    int wg = ba*NCHUNK + cch;
    s   += psums[(size_t)wg*IT*Dn + i*Dn + d];
    cnt += pcnts[wg*IT + i];
  }
  float div = cnt > 0.f ? cnt : 1.f;
  pooled[gid] = s / div;
  if (d == 0) empty[seg] = (cnt == 0.f) ? 1.f : 0.f;
}

extern "C" void kernel_launch(void* const* d_in, const int* in_sizes, int n_in,
                              void* d_out, int out_size, void* d_ws, size_t ws_size,
                              hipStream_t stream) {
  // inputs: [0] attention_mask (unused), [1] hidden f32, [2] attr i32, [3] item i32,
  //         [4] W f32, [5] b f32
  const float* hidden = (const float*)d_in[1];
  const int*   attr   = (const int*)  d_in[2];
  const int*   item   = (const int*)  d_in[3];
  const float* W      = (const float*)d_in[4];
  const float* bias   = (const float*)d_in[5];

  // outputs: pooled [16,8,32,128] f32, empty [16,8,32] (bool->1.0/0.0), h [16,2048,128] f32
  float* pooled = (float*)d_out;
  float* empty  = pooled + (size_t)NSEG*Dn;          // +524288
  float* Hout   = empty  + NSEG;                     // +4096

  // workspace: Wt bf16 (196608 B) | partial sums 1024*4096 f32 (16 MB) | partial counts
  unsigned short* Wt = (unsigned short*)d_ws;
  float* psums = (float*)((char*)d_ws + 196608);
  float* pcnts = psums + (size_t)Bn*AT*NCHUNK*IT*Dn; // 1024*4096 floats
  // total ws use ~17.1 MB (all fully written before read each call)

  k_prep<<<(Hn*Dn + 255)/256, 256, 0, stream>>>(W, Wt);
  k_gemm<<<(Bn*Sn)/64, 256, 0, stream>>>(hidden, Wt, bias, Hout);
  k_scan<<<Bn*AT*NCHUNK, 128, 0, stream>>>(attr, item, Hout, psums, pcnts);
  k_comb<<<(NSEG*Dn)/256, 256, 0, stream>>>(psums, pcnts, pooled, empty);
}

// Round 2
// 42.269 us; speedup vs baseline: 1.0280x; 1.0280x over previous
//
#include <hip/hip_runtime.h>
#include <hip/hip_bf16.h>

#define Bn 16
#define Sn 2048
#define Hn 768
#define Dn 128
#define AT 8
#define IT 32
#define NSEG (Bn*AT*IT)      // 4096

typedef __attribute__((ext_vector_type(4))) float f32x4;
typedef __attribute__((ext_vector_type(2))) float f32x2;
typedef __attribute__((ext_vector_type(4))) int   i32x4;
typedef __attribute__((ext_vector_type(8))) short bf16x8;
typedef __attribute__((ext_vector_type(4))) short s16x4;

__device__ __forceinline__ unsigned short f2bf(float f){
  union { float f; unsigned u; } v; v.f = f;
  unsigned r = v.u + 0x7FFFu + ((v.u >> 16) & 1u);   // round-to-nearest-even
  return (unsigned short)(r >> 16);
}

// ---- kernel 0: W [H][D] fp32 -> Wt [D][H] bf16 (transposed, for contiguous B-fragments) ----
__global__ __launch_bounds__(256) void k_prep(const float* __restrict__ W,
                                              unsigned short* __restrict__ Wt){
  int gid = blockIdx.x*256 + threadIdx.x;
  if (gid >= Hn*Dn) return;
  int d = gid / Hn;
  int k = gid - d*Hn;
  Wt[gid] = f2bf(W[k*Dn + d]);
}

// ---- kernel 1: h = X @ W + b  (bf16 MFMA 16x16x32, fp32 out) ----
// BM=64, BN=128(all of D), BK=64. 256 threads = 4 waves; wave w -> cols [w*32, w*32+32).
// LDS tiles XOR-swizzled (byte ^= (row&7)<<4) so ds_read_b128 fragments are conflict-free.
__global__ __launch_bounds__(256) void k_gemm(const float* __restrict__ X,
        const unsigned short* __restrict__ Wt, const float* __restrict__ bias,
        float* __restrict__ Hout){
  __shared__ unsigned char sA[2][64*128];    // [row][128B of swizzled bf16 k]
  __shared__ unsigned char sB[2][128*128];   // [col][128B of swizzled bf16 k]
  const int tid  = threadIdx.x;
  const int lane = tid & 63;
  const int wave = tid >> 6;
  const int m0 = blockIdx.x * 64;

  // staging maps
  const int ar = tid >> 2, akq = tid & 3;    // A: row, k-quarter
  const int bc = tid >> 1, bkh = tid & 1;    // B: col, k-half
  const float*          Ap = X  + (size_t)(m0 + ar)*Hn + akq*4;
  const unsigned short* Bp = Wt + (size_t)bc*Hn + bkh*32;

  int aw[4], bw[4];
  #pragma unroll
  for (int c=0;c<4;c++) aw[c] = ar*128 + ((akq*8 + c*32) ^ ((ar&7)<<4));   // 8B chunks
  #pragma unroll
  for (int c=0;c<4;c++) bw[c] = bc*128 + ((bkh*64 + c*16) ^ ((bc&7)<<4));  // 16B chunks

  // fragment read bases
  int abase[4], aswz[4];
  #pragma unroll
  for (int mi=0;mi<4;mi++){
    int row = mi*16 + (lane&15);
    abase[mi] = row*128; aswz[mi] = (row&7)<<4;
  }
  int bbase[2], bswz[2];
  #pragma unroll
  for (int ni=0;ni<2;ni++){
    int col = wave*32 + ni*16 + (lane&15);
    bbase[ni] = col*128; bswz[ni] = (col&7)<<4;
  }
  const int kblk = (lane>>4)*16;

  f32x4 acc[4][2];
  #pragma unroll
  for (int mi=0;mi<4;mi++)
    #pragma unroll
    for (int ni=0;ni<2;ni++) acc[mi][ni] = (f32x4){0.f,0.f,0.f,0.f};

  f32x4 av[4]; i32x4 bv[4];
  // prologue: stage K-step 0 into buffer 0
  #pragma unroll
  for (int c=0;c<4;c++) av[c] = *(const f32x4*)(Ap + c*16);
  #pragma unroll
  for (int c=0;c<4;c++) bv[c] = *(const i32x4*)(Bp + c*8);
  #pragma unroll
  for (int c=0;c<4;c++){
    s16x4 t;
    t[0]=(short)f2bf(av[c][0]); t[1]=(short)f2bf(av[c][1]);
    t[2]=(short)f2bf(av[c][2]); t[3]=(short)f2bf(av[c][3]);
    *(s16x4*)&sA[0][aw[c]] = t;
  }
  #pragma unroll
  for (int c=0;c<4;c++) *(i32x4*)&sB[0][bw[c]] = bv[c];
  __syncthreads();

  int cur = 0;
  for (int step=0; step<12; ++step){
    if (step < 11){  // prefetch next K-step to regs (latency hides under MFMA)
      #pragma unroll
      for (int c=0;c<4;c++) av[c] = *(const f32x4*)(Ap + (step+1)*64 + c*16);
      #pragma unroll
      for (int c=0;c<4;c++) bv[c] = *(const i32x4*)(Bp + (step+1)*64 + c*8);
    }
    #pragma unroll
    for (int ks=0; ks<2; ++ks){
      bf16x8 af[4], bfv[2];
      #pragma unroll
      for (int mi=0;mi<4;mi++)
        af[mi] = *(const bf16x8*)&sA[cur][abase[mi] + ((ks*64 + kblk) ^ aswz[mi])];
      #pragma unroll
      for (int ni=0;ni<2;ni++)
        bfv[ni] = *(const bf16x8*)&sB[cur][bbase[ni] + ((ks*64 + kblk) ^ bswz[ni])];
      #pragma unroll
      for (int mi=0;mi<4;mi++)
        #pragma unroll
        for (int ni=0;ni<2;ni++)
          acc[mi][ni] = __builtin_amdgcn_mfma_f32_16x16x32_bf16(af[mi], bfv[ni], acc[mi][ni], 0, 0, 0);
    }
    if (step < 11){  // write next tile to other buffer (WAR-safe: prev barrier separates)
      #pragma unroll
      for (int c=0;c<4;c++){
        s16x4 t;
        t[0]=(short)f2bf(av[c][0]); t[1]=(short)f2bf(av[c][1]);
        t[2]=(short)f2bf(av[c][2]); t[3]=(short)f2bf(av[c][3]);
        *(s16x4*)&sA[cur^1][aw[c]] = t;
      }
      #pragma unroll
      for (int c=0;c<4;c++) *(i32x4*)&sB[cur^1][bw[c]] = bv[c];
    }
    __syncthreads();
    cur ^= 1;
  }

  // epilogue: C/D layout col=lane&15, row=(lane>>4)*4+r  (m89-verified)
  #pragma unroll
  for (int ni=0;ni<2;ni++){
    int col = wave*32 + ni*16 + (lane&15);
    float bb = bias[col];
    #pragma unroll
    for (int mi=0;mi<4;mi++){
      int row0 = m0 + mi*16 + (lane>>4)*4;
      #pragma unroll
      for (int r=0;r<4;r++)
        Hout[(size_t)(row0 + r)*Dn + col] = acc[mi][ni][r] + bb;
    }
  }
}

// ---- kernel 2: per-(batch,attr) segment mean, writes pooled + empty directly ----
// One WG per (b,a); 4 waves each own a 512-token quarter: ballot-compact an
// ordered list, accumulate matched h rows into a private LDS accumulator
// (deterministic order), then tree-combine + divide. Counts via int LDS atomics.
__global__ __launch_bounds__(256) void k_scan(const int* __restrict__ attr,
        const int* __restrict__ item, const float* __restrict__ Hsrc,
        float* __restrict__ pooled, float* __restrict__ empty){
  __shared__ float ssum[4][IT][Dn];   // 64 KB, one slab per wave
  __shared__ int   slist[4][512];     // 8 KB ordered match lists
  __shared__ int   scnt[IT];

  const int wg  = blockIdx.x;        // b*8 + a
  const int a   = wg & 7;
  const int b   = wg >> 3;
  const int tid = threadIdx.x;       // 0..255
  const int wv  = tid >> 6;
  const int lane = tid & 63;

  for (int i = tid; i < 4*IT*Dn; i += 256) (&ssum[0][0][0])[i] = 0.f;
  if (tid < IT) scnt[tid] = 0;
  __syncthreads();

  // build this wave's ordered match list over its 512-token quarter
  const int tok0 = wv * 512;
  const int gbase = b * Sn;
  int nm = 0;
  #pragma unroll
  for (int g = 0; g < 8; ++g){
    int tok = tok0 + g*64 + lane;
    int avv = attr[gbase + tok], ivv = item[gbase + tok];
    bool m = (avv == a+1) && (ivv >= 1) && (ivv <= IT);
    unsigned long long mask = __ballot(m);
    int pos = nm + __popcll(mask & ((1ull << lane) - 1ull));
    if (m){
      slist[wv][pos] = ((ivv-1) << 16) | tok;
      atomicAdd(&scnt[ivv-1], 1);            // int, order-independent
    }
    nm += __popcll(mask);
  }

  // accumulate: lane owns dims (2*lane, 2*lane+1); 8-deep load pipeline
  const f32x2* hb = (const f32x2*)(Hsrc + (size_t)b*Sn*Dn);
  float* myacc = &ssum[wv][0][0];
  int e = 0;
  for (; e + 8 <= nm; e += 8){
    int idx[8]; f32x2 v[8];
    #pragma unroll
    for (int j=0;j<8;j++) idx[j] = slist[wv][e+j];
    #pragma unroll
    for (int j=0;j<8;j++) v[j] = hb[(size_t)(idx[j] & 0xffff)*64 + lane];
    #pragma unroll
    for (int j=0;j<8;j++){
      f32x2* p = (f32x2*)&myacc[(idx[j]>>16)*Dn + lane*2];
      f32x2 old = *p; old[0] += v[j][0]; old[1] += v[j][1]; *p = old;
    }
  }
  for (; e < nm; ++e){
    int idx = slist[wv][e];
    f32x2 v = hb[(size_t)(idx & 0xffff)*64 + lane];
    f32x2* p = (f32x2*)&myacc[(idx>>16)*Dn + lane*2];
    f32x2 old = *p; old[0] += v[0]; old[1] += v[1]; *p = old;
  }
  __syncthreads();

  // combine 4 wave-slabs (fixed order), divide, write
  float* outp = pooled + (size_t)wg*IT*Dn;
  for (int o = tid; o < IT*Dn; o += 256){
    int i = o >> 7, d = o & 127;
    float s = ssum[0][i][d] + ssum[1][i][d] + ssum[2][i][d] + ssum[3][i][d];
    int cnt = scnt[i];
    outp[o] = s / (float)(cnt > 0 ? cnt : 1);
  }
  if (tid < IT) empty[wg*IT + tid] = (scnt[tid] == 0) ? 1.f : 0.f;
}

extern "C" void kernel_launch(void* const* d_in, const int* in_sizes, int n_in,
                              void* d_out, int out_size, void* d_ws, size_t ws_size,
                              hipStream_t stream) {
  // inputs: [0] attention_mask (unused), [1] hidden f32, [2] attr i32, [3] item i32,
  //         [4] W f32, [5] b f32
  const float* hidden = (const float*)d_in[1];
  const int*   attr   = (const int*)  d_in[2];
  const int*   item   = (const int*)  d_in[3];
  const float* W      = (const float*)d_in[4];
  const float* bias   = (const float*)d_in[5];

  // outputs: pooled [16,8,32,128] f32, empty [16,8,32] (1.0/0.0), h [16,2048,128] f32
  float* pooled = (float*)d_out;
  float* empty  = pooled + (size_t)NSEG*Dn;          // +524288
  float* Hout   = empty  + NSEG;                     // +4096

  // workspace: Wt bf16 (196608 B)
  unsigned short* Wt = (unsigned short*)d_ws;

  k_prep<<<(Hn*Dn + 255)/256, 256, 0, stream>>>(W, Wt);
  k_gemm<<<(Bn*Sn)/64, 256, 0, stream>>>(hidden, Wt, bias, Hout);
  k_scan<<<Bn*AT, 256, 0, stream>>>(attr, item, Hout, pooled, empty);
}

// Round 3
// 39.429 us; speedup vs baseline: 1.1020x; 1.0720x over previous
//
#include <hip/hip_runtime.h>
#include <hip/hip_bf16.h>

#define Bn 16
#define Sn 2048
#define Hn 768
#define Dn 128
#define AT 8
#define IT 32
#define NSEG (Bn*AT*IT)      // 4096

typedef __attribute__((ext_vector_type(4))) float f32x4;
typedef __attribute__((ext_vector_type(4))) int   i32x4;
typedef __attribute__((ext_vector_type(8))) short bf16x8;
typedef __attribute__((ext_vector_type(4))) short s16x4;

__device__ __forceinline__ unsigned short f2bf(float f){
  union { float f; unsigned u; } v; v.f = f;
  unsigned r = v.u + 0x7FFFu + ((v.u >> 16) & 1u);   // round-to-nearest-even
  return (unsigned short)(r >> 16);
}

// ---- kernel 0: W [768][128] f32 -> Wt [128][768] bf16, LDS-tiled transpose ----
// 24 WGs, each a 64k x 64d tile. Coalesced f32x4 reads; [64][65] pad (2-way max
// on transposed reads); packed s16x4 (8B) coalesced writes.
__global__ __launch_bounds__(256) void k_prep(const float* __restrict__ W,
                                              unsigned short* __restrict__ Wt){
  __shared__ float sT[64][65];
  const int tid = threadIdx.x;
  const int k0 = (blockIdx.x % 12) * 64;
  const int d0 = (blockIdx.x / 12) * 64;
  const int rr = tid >> 4;          // 0..15
  const int cg = tid & 15;          // 0..15 -> 4 cols

  #pragma unroll
  for (int p = 0; p < 4; ++p){
    int k = rr + p*16;
    f32x4 v = *(const f32x4*)&W[(size_t)(k0 + k)*Dn + d0 + cg*4];
    sT[k][cg*4+0] = v[0]; sT[k][cg*4+1] = v[1];
    sT[k][cg*4+2] = v[2]; sT[k][cg*4+3] = v[3];
  }
  __syncthreads();
  #pragma unroll
  for (int p = 0; p < 4; ++p){
    int d = rr + p*16;
    s16x4 t;
    #pragma unroll
    for (int j = 0; j < 4; ++j) t[j] = (short)f2bf(sT[cg*4+j][d]);
    *(s16x4*)&Wt[(size_t)(d0 + d)*Hn + k0 + cg*4] = t;
  }
}

// ---- kernel 1: h = X @ W + b  (bf16 MFMA 16x16x32, fp32 out) ----
// BM=64, BN=128(all of D), BK=64. 256 threads = 4 waves; wave w -> cols [w*32, w*32+32).
// LDS tiles XOR-swizzled (byte ^= (row&7)<<4) so ds_read_b128 fragments are conflict-free.
__global__ __launch_bounds__(256) void k_gemm(const float* __restrict__ X,
        const unsigned short* __restrict__ Wt, const float* __restrict__ bias,
        float* __restrict__ Hout){
  __shared__ unsigned char sA[2][64*128];    // [row][128B of swizzled bf16 k]
  __shared__ unsigned char sB[2][128*128];   // [col][128B of swizzled bf16 k]
  const int tid  = threadIdx.x;
  const int lane = tid & 63;
  const int wave = tid >> 6;
  const int m0 = blockIdx.x * 64;

  // staging maps
  const int ar = tid >> 2, akq = tid & 3;    // A: row, k-quarter
  const int bc = tid >> 1, bkh = tid & 1;    // B: col, k-half
  const float*          Ap = X  + (size_t)(m0 + ar)*Hn + akq*4;
  const unsigned short* Bp = Wt + (size_t)bc*Hn + bkh*32;

  int aw[4], bw[4];
  #pragma unroll
  for (int c=0;c<4;c++) aw[c] = ar*128 + ((akq*8 + c*32) ^ ((ar&7)<<4));   // 8B chunks
  #pragma unroll
  for (int c=0;c<4;c++) bw[c] = bc*128 + ((bkh*64 + c*16) ^ ((bc&7)<<4));  // 16B chunks

  // fragment read bases
  int abase[4], aswz[4];
  #pragma unroll
  for (int mi=0;mi<4;mi++){
    int row = mi*16 + (lane&15);
    abase[mi] = row*128; aswz[mi] = (row&7)<<4;
  }
  int bbase[2], bswz[2];
  #pragma unroll
  for (int ni=0;ni<2;ni++){
    int col = wave*32 + ni*16 + (lane&15);
    bbase[ni] = col*128; bswz[ni] = (col&7)<<4;
  }
  const int kblk = (lane>>4)*16;

  f32x4 acc[4][2];
  #pragma unroll
  for (int mi=0;mi<4;mi++)
    #pragma unroll
    for (int ni=0;ni<2;ni++) acc[mi][ni] = (f32x4){0.f,0.f,0.f,0.f};

  f32x4 av[4]; i32x4 bv[4];
  // prologue: stage K-step 0 into buffer 0
  #pragma unroll
  for (int c=0;c<4;c++) av[c] = *(const f32x4*)(Ap + c*16);
  #pragma unroll
  for (int c=0;c<4;c++) bv[c] = *(const i32x4*)(Bp + c*8);
  #pragma unroll
  for (int c=0;c<4;c++){
    s16x4 t;
    t[0]=(short)f2bf(av[c][0]); t[1]=(short)f2bf(av[c][1]);
    t[2]=(short)f2bf(av[c][2]); t[3]=(short)f2bf(av[c][3]);
    *(s16x4*)&sA[0][aw[c]] = t;
  }
  #pragma unroll
  for (int c=0;c<4;c++) *(i32x4*)&sB[0][bw[c]] = bv[c];
  __syncthreads();

  int cur = 0;
  for (int step=0; step<12; ++step){
    if (step < 11){  // prefetch next K-step to regs (latency hides under MFMA)
      #pragma unroll
      for (int c=0;c<4;c++) av[c] = *(const f32x4*)(Ap + (step+1)*64 + c*16);
      #pragma unroll
      for (int c=0;c<4;c++) bv[c] = *(const i32x4*)(Bp + (step+1)*64 + c*8);
    }
    #pragma unroll
    for (int ks=0; ks<2; ++ks){
      bf16x8 af[4], bfv[2];
      #pragma unroll
      for (int mi=0;mi<4;mi++)
        af[mi] = *(const bf16x8*)&sA[cur][abase[mi] + ((ks*64 + kblk) ^ aswz[mi])];
      #pragma unroll
      for (int ni=0;ni<2;ni++)
        bfv[ni] = *(const bf16x8*)&sB[cur][bbase[ni] + ((ks*64 + kblk) ^ bswz[ni])];
      #pragma unroll
      for (int mi=0;mi<4;mi++)
        #pragma unroll
        for (int ni=0;ni<2;ni++)
          acc[mi][ni] = __builtin_amdgcn_mfma_f32_16x16x32_bf16(af[mi], bfv[ni], acc[mi][ni], 0, 0, 0);
    }
    if (step < 11){  // write next tile to other buffer (WAR-safe: prev barrier separates)
      #pragma unroll
      for (int c=0;c<4;c++){
        s16x4 t;
        t[0]=(short)f2bf(av[c][0]); t[1]=(short)f2bf(av[c][1]);
        t[2]=(short)f2bf(av[c][2]); t[3]=(short)f2bf(av[c][3]);
        *(s16x4*)&sA[cur^1][aw[c]] = t;
      }
      #pragma unroll
      for (int c=0;c<4;c++) *(i32x4*)&sB[cur^1][bw[c]] = bv[c];
    }
    __syncthreads();
    cur ^= 1;
  }

  // epilogue: C/D layout col=lane&15, row=(lane>>4)*4+r  (m89-verified)
  #pragma unroll
  for (int ni=0;ni<2;ni++){
    int col = wave*32 + ni*16 + (lane&15);
    float bb = bias[col];
    #pragma unroll
    for (int mi=0;mi<4;mi++){
      int row0 = m0 + mi*16 + (lane>>4)*4;
      #pragma unroll
      for (int r=0;r<4;r++)
        Hout[(size_t)(row0 + r)*Dn + col] = acc[mi][ni][r] + bb;
    }
  }
}

// ---- kernel 2: per-(batch,attr,dim-half) segment mean -> pooled + empty ----
// 256 WGs (all CUs). 4 waves; wave wv owns tokens [wv*512,wv*512+512) with a
// private ballot-ordered list and private 8KB LDS slab (deterministic order).
// Lane owns one dim. Counts via int LDS atomics (order-independent).
__global__ __launch_bounds__(256) void k_scan(const int* __restrict__ attr,
        const int* __restrict__ item, const float* __restrict__ Hsrc,
        float* __restrict__ pooled, float* __restrict__ empty){
  __shared__ float ssum[4][IT][64];   // 32 KB, one slab per wave
  __shared__ int   slist[4][512];     // 8 KB ordered match lists
  __shared__ int   scnt[IT];

  const int wg  = blockIdx.x;        // (b*8 + a)*2 + dh
  const int dh  = wg & 1;
  const int a   = (wg >> 1) & 7;
  const int b   = wg >> 4;
  const int tid = threadIdx.x;       // 0..255
  const int wv  = tid >> 6;
  const int lane = tid & 63;

  // zero own slab (wave-local; no barrier needed before accumulate)
  #pragma unroll
  for (int i = 0; i < IT; ++i) ssum[wv][i][lane] = 0.f;
  if (tid < IT) scnt[tid] = 0;

  // build this wave's ordered match list over its 512-token range
  const int tok0 = wv * 512;
  const int gbase = b * Sn;
  int nm = 0;
  #pragma unroll
  for (int g = 0; g < 8; ++g){
    int tok = tok0 + g*64 + lane;
    int avv = attr[gbase + tok], ivv = item[gbase + tok];
    bool m = (avv == a+1) && (ivv >= 1) && (ivv <= IT);
    unsigned long long mask = __ballot(m);
    int pos = nm + __popcll(mask & ((1ull << lane) - 1ull));
    if (m) slist[wv][pos] = ((ivv-1) << 16) | tok;
    nm += __popcll(mask);
  }
  __syncthreads();   // scnt zeros visible

  // counts (each token counted once per WG; both dim-halves compute identical counts)
  for (int e = lane; e < nm; e += 64) atomicAdd(&scnt[slist[wv][e] >> 16], 1);

  // accumulate: lane owns dim dh*64+lane; 8-deep load batches
  const float* hb = Hsrc + (size_t)b*Sn*Dn + dh*64 + lane;
  int e = 0;
  for (; e + 8 <= nm; e += 8){
    int idx[8]; float v[8];
    #pragma unroll
    for (int j=0;j<8;j++) idx[j] = slist[wv][e+j];
    #pragma unroll
    for (int j=0;j<8;j++) v[j] = hb[(size_t)(idx[j] & 0xffff)*Dn];
    #pragma unroll
    for (int j=0;j<8;j++) ssum[wv][idx[j]>>16][lane] += v[j];
  }
  for (; e < nm; ++e){
    int idx = slist[wv][e];
    ssum[wv][idx>>16][lane] += hb[(size_t)(idx & 0xffff)*Dn];
  }
  __syncthreads();

  // combine 4 wave-slabs (fixed order), divide, write
  float* outp = pooled + (size_t)(b*AT + a)*IT*Dn + dh*64;
  for (int o = tid; o < IT*64; o += 256){
    int i = o >> 6, d = o & 63;
    float s = ssum[0][i][d] + ssum[1][i][d] + ssum[2][i][d] + ssum[3][i][d];
    int cnt = scnt[i];
    outp[i*Dn + d] = s / (float)(cnt > 0 ? cnt : 1);
  }
  if (dh == 0 && tid < IT)
    empty[(b*AT + a)*IT + tid] = (scnt[tid] == 0) ? 1.f : 0.f;
}

extern "C" void kernel_launch(void* const* d_in, const int* in_sizes, int n_in,
                              void* d_out, int out_size, void* d_ws, size_t ws_size,
                              hipStream_t stream) {
  // inputs: [0] attention_mask (unused), [1] hidden f32, [2] attr i32, [3] item i32,
  //         [4] W f32, [5] b f32
  const float* hidden = (const float*)d_in[1];
  const int*   attr   = (const int*)  d_in[2];
  const int*   item   = (const int*)  d_in[3];
  const float* W      = (const float*)d_in[4];
  const float* bias   = (const float*)d_in[5];

  // outputs: pooled [16,8,32,128] f32, empty [16,8,32] (1.0/0.0), h [16,2048,128] f32
  float* pooled = (float*)d_out;
  float* empty  = pooled + (size_t)NSEG*Dn;          // +524288
  float* Hout   = empty  + NSEG;                     // +4096

  // workspace: Wt bf16 (196608 B)
  unsigned short* Wt = (unsigned short*)d_ws;

  k_prep<<<24, 256, 0, stream>>>(W, Wt);
  k_gemm<<<(Bn*Sn)/64, 256, 0, stream>>>(hidden, Wt, bias, Hout);
  k_scan<<<Bn*AT*2, 256, 0, stream>>>(attr, item, Hout, pooled, empty);
}